// Round 12
// baseline (140.804 us; speedup 1.0000x reference)
//
#include <hip/hip_runtime.h>
#include <cmath>

#define T_STEPS 384
#define CH 64
#define NCH 6
#define WS 392   // replica stride (layout identical to R9; conflicts measured ~0.4us/block, secondary)

__device__ __forceinline__ float readlane_f(float v, int l) {
    return __int_as_float(__builtin_amdgcn_readlane(__float_as_int(v), l));
}

// DPP wave shift-right by 1: dst lane i = src lane i-1, lane 0 = 0 (bound_ctrl).
__device__ __forceinline__ float wave_shr1_f(float v) {
    return __int_as_float(__builtin_amdgcn_mov_dpp(__float_as_int(v), 0x138, 0xf, 0xf, true));
}

// R9 skeleton (best measured: ~24us kernel), but each block now owns TWO
// neurons (2s, 2s+1). Wave 0 interleaves both neurons' serial step chains in
// one instruction stream (independent -> pure ILP to fill the ~150cyc/step
// stall R11's counters exposed; added waves demonstrably don't fill it).
// Wave 1 produces both neurons' g>=2 far fields (source-major, it has slack).
// Per-neuron FP op order is untouched vs R9 => bit-identical (absmax 0.5).
__global__ __launch_bounds__(128, 2)
void flif_kernel(const float* __restrict__ I_old, const float* __restrict__ W,
                 float* __restrict__ out, float cm1, float c2, float c3, int Stot)
{
    const int tid  = threadIdx.x;
    const int wid  = tid >> 6;
    const int lane = tid & 63;
    const int nA   = 2 * blockIdx.x;      // neuron A row
    const int nB   = nA + 1;              // neuron B row

    __shared__ __align__(16) float wtr[4 * WS];       // wtr[r][k] = wt[k+r], wt[i]=wr[i+1]=W[4998-i]
    __shared__ __align__(16) float dbuf[2][T_STEPS];  // delta history per neuron
    __shared__ float accs[2][2][CH];                  // [neuron][target parity][lane]

    for (int k = tid; k < 4 * WS; k += 128) {
        const int r = k / WS, kk = k - r * WS;
        const int i = kk + r;
        wtr[k] = (i <= 382) ? W[4998 - i] : 0.0f;
    }
    ((float*)accs)[tid] = 0.0f;                       // zero all 256 floats
    ((float*)accs)[tid + 128] = 0.0f;
    __syncthreads();

    // ascending per-lane weight base: wlp[m] = wt[lane + m], 16B-aligned for m%4==0
    const int rl = lane & 3;
    const float* wlp = wtr + rl * WS + (lane - rl);

    if (wid == 1) {
        // -------- far-field producer wave: g>=2, source-major, BOTH neurons --------
        float A2a = 0, A3a = 0, A4a = 0, A5a = 0;
        float A2b = 0, A3b = 0, A4b = 0, A5b = 0;
        #pragma unroll
        for (int c = 0; c < NCH; ++c) {
            if (c >= 1 && c <= 4) {
                const int src = c - 1;                // deltas published at end of chunk c-1
                #pragma unroll
                for (int X = 0; X < 2; ++X) {
                    const float* dp = dbuf[X] + src * CH;
                    #pragma unroll
                    for (int k = 0; k <= 60; k += 4) {
                        const float4 d4 = *reinterpret_cast<const float4*>(dp + k);   // broadcast
                        #pragma unroll
                        for (int t = c + 1; t <= 5; ++t) {
                            const int g = t - src;                                    // 2..5
                            const float4 w4 = *reinterpret_cast<const float4*>(wlp + (g * 64 - k - 4));
                            float& At = (X == 0)
                                ? ((t == 2) ? A2a : (t == 3) ? A3a : (t == 4) ? A4a : A5a)
                                : ((t == 2) ? A2b : (t == 3) ? A3b : (t == 4) ? A4b : A5b);
                            At = fmaf(d4.x, w4.w, At);   // j ascending within each target
                            At = fmaf(d4.y, w4.z, At);
                            At = fmaf(d4.z, w4.y, At);
                            At = fmaf(d4.w, w4.x, At);
                        }
                    }
                    const float hand = (X == 0)
                        ? ((c == 1) ? A2a : (c == 2) ? A3a : (c == 3) ? A4a : A5a)
                        : ((c == 1) ? A2b : (c == 2) ? A3b : (c == 3) ? A4b : A5b);
                    accs[X][(c + 1) & 1][lane] = hand;   // target c+1 complete
                }
            }
            __syncthreads();
        }
        return;
    }

    // -------- step-loop wave (wid == 0): two interleaved neurons --------
    const float* IrowA = I_old + (size_t)nA * T_STEPS;
    const float* IrowB = I_old + (size_t)nB * T_STEPS;
    float InextA = IrowA[lane];
    float InextB = IrowB[lane];
    const float w0   = (lane >= 1) ? W[4999 - lane] : 0.0f;  // wr[lane], wr[0]=0
    const float wr1n = -W[4998];                             // -wr[1]

    float VA = 0, dA = 0, bA = 0, PA = 0;
    float VB = 0, dB = 0, bB = 0, PB = 0;
    float tcsA[NCH], spksA[NCH], tcsB[NCH], spksB[NCH];

    for (int c = 0; c < NCH; ++c) {
        const int cb = c * CH;
        const float IcA = InextA, IcB = InextB;
        if (c + 1 < NCH) { InextA = IrowA[cb + CH + lane]; InextB = IrowB[cb + CH + lane]; }

        // ---- far field: g>=2 partial from producer, then append g=1 (j ascending) ----
        float accA = (c == 0) ? 0.0f : accs[0][c & 1][lane];
        float accB = (c == 0) ? 0.0f : accs[1][c & 1][lane];
        if (c >= 1) {
            const float* dpA = dbuf[0] + (c - 1) * CH;
            const float* dpB = dbuf[1] + (c - 1) * CH;
            #pragma unroll
            for (int m0 = 60; m0 >= 0; m0 -= 4) {
                const float4 w4 = *reinterpret_cast<const float4*>(wlp + m0);          // shared
                const float4 a4 = *reinterpret_cast<const float4*>(dpA + (60 - m0));   // broadcast
                const float4 b4 = *reinterpret_cast<const float4*>(dpB + (60 - m0));
                accA = fmaf(a4.x, w4.w, accA);  accB = fmaf(b4.x, w4.w, accB);
                accA = fmaf(a4.y, w4.z, accA);  accB = fmaf(b4.y, w4.z, accB);
                accA = fmaf(a4.z, w4.y, accA);  accB = fmaf(b4.z, w4.y, accB);
                accA = fmaf(a4.w, w4.x, accA);  accB = fmaf(b4.w, w4.x, accB);
            }
        }

        float uA = fmaf(c3, IcA, c2) - accA;
        float uB = fmaf(c3, IcB, c2) - accB;
        const float VsA = VA, VsB = VB;
        float tcA = 0.0f, tcB = 0.0f;
        float wA = w0, wB = w0;

        auto body = [&](int i) {
            // neuron A                                  // neuron B (independent -> ILP)
            const float tA = fmaf(wr1n, dA, PA);         const float tB = fmaf(wr1n, dB, PB);
            dA = tA + bA;                                dB = tB + bB;
            PA = readlane_f(uA, (i + 1) & 63);           PB = readlane_f(uB, (i + 1) & 63);
            VA = VA + dA;                                VB = VB + dB;
            const float rA = (VA > -50.0f) ? -20.0f : 0.0f;
            const float rB = (VB > -50.0f) ? -20.0f : 0.0f;
            bA = fmaf(cm1, VA, rA);                      bB = fmaf(cm1, VB, rB);
            uA = fmaf(-wA, dA, uA);                      uB = fmaf(-wB, dB, uB);
            wA = wave_shr1_f(wA);                        wB = wave_shr1_f(wB);
            tcA = (lane == i) ? VA : tcA;                tcB = (lane == i) ? VB : tcB;
        };

        if (c == 0) {
            // step 0: V_prev=0 -> spike, V_pre=-70, V_new=-90; delta masked out
            VA = -90.0f; VB = -90.0f;
            if (lane == 0) { tcA = VA; tcB = VB; }
            wA = wave_shr1_f(wA); wB = wave_shr1_f(wB);  // -> wr[lane-1]
            // step 1: V1 rule (no memory); V=-90 -> no reset
            const float I1A = readlane_f(IcA, 1);
            const float I1B = readlane_f(IcB, 1);
            const float V1A = fmaf(0.005f, (I1A / 0.025f) - VA, VA);
            const float V1B = fmaf(0.005f, (I1B / 0.025f) - VB, VB);
            const float d1A = V1A - VA, d1B = V1B - VB;
            PA = readlane_f(uA, 2); PB = readlane_f(uB, 2);
            uA = fmaf(-wA, d1A, uA); uB = fmaf(-wB, d1B, uB);
            wA = wave_shr1_f(wA); wB = wave_shr1_f(wB);  // -> wr[lane-2]
            if (lane == 1) { tcA = V1A; tcB = V1B; }
            VA = V1A; VB = V1B; dA = d1A; dB = d1B;
            bA = fmaf(cm1, VA, (VA > -50.0f) ? -20.0f : 0.0f);
            bB = fmaf(cm1, VB, (VB > -50.0f) ? -20.0f : 0.0f);
            #pragma unroll
            for (int i = 2; i < CH; ++i) body(i);
        } else {
            dA = 0.0f; dB = 0.0f;                        // wr[1]*d_{cb-1} already in far field
            PA = readlane_f(uA, 0); PB = readlane_f(uB, 0);
            #pragma unroll
            for (int i = 0; i < CH; ++i) body(i);
        }

        // ---- chunk epilogue: prev-V per lane -> spike, delta; publish dbuf ----
        float prevA = __shfl_up(tcA, 1);
        float prevB = __shfl_up(tcB, 1);
        if (lane == 0) { prevA = VsA; prevB = VsB; }
        spksA[c] = (prevA > -50.0f) ? 1.0f : 0.0f;
        spksB[c] = (prevB > -50.0f) ? 1.0f : 0.0f;
        float ddA = tcA - prevA, ddB = tcB - prevB;
        if (c == 0 && lane == 0) { ddA = 0.0f; ddB = 0.0f; }   // delta_0 excluded
        dbuf[0][cb + lane] = ddA;
        dbuf[1][cb + lane] = ddB;
        tcsA[c] = tcA; tcsB[c] = tcB;
        __syncthreads();                                 // publish dbuf / consume accs
    }

    // ---- deferred global stores (off the barrier path) ----
    float* spkA = out + (size_t)nA * T_STEPS;
    float* spkB = out + (size_t)nB * T_STEPS;
    float* trcA = out + (size_t)Stot * T_STEPS + (size_t)nA * T_STEPS;
    float* trcB = out + (size_t)Stot * T_STEPS + (size_t)nB * T_STEPS;
    #pragma unroll
    for (int c = 0; c < NCH; ++c) {
        spkA[c * CH + lane] = spksA[c];
        spkB[c * CH + lane] = spksB[c];
        trcA[c * CH + lane] = tcsA[c];
        trcB[c * CH + lane] = tcsB[c];
    }
}

extern "C" void kernel_launch(void* const* d_in, const int* in_sizes, int n_in,
                              void* d_out, int out_size, void* d_ws, size_t ws_size,
                              hipStream_t stream) {
    const float* I = (const float*)d_in[0];
    const float* W = (const float*)d_in[1];
    float* out = (float*)d_out;
    const int S = in_sizes[0] / T_STEPS;   // 2048

    const double COEF = std::pow(0.1, 0.15) * std::tgamma(1.85) / 0.5;
    const float c3  = (float)COEF;                     // COEF
    const float cm1 = (float)(-COEF * 0.025);          // c1 - 1 = -COEF*GL
    const float c2  = (float)(COEF * 0.025 * -70.0);   // COEF*GL*VL

    flif_kernel<<<S / 2, 128, 0, stream>>>(I, W, out, cm1, c2, c3, S);
}

// Round 13
// 112.065 us; speedup vs baseline: 1.2564x; 1.2564x over previous
//
#include <hip/hip_runtime.h>
#include <cmath>

#define T_STEPS 384
#define CH 64
#define NCH 6
#define WS 392   // replica stride (layout identical to R9)

__device__ __forceinline__ float readlane_f(float v, int l) {
    return __int_as_float(__builtin_amdgcn_readlane(__float_as_int(v), l));
}

// DPP wave shift-right by 1: dst lane i = src lane i-1, lane 0 = 0 (bound_ctrl).
__device__ __forceinline__ float wave_shr1_f(float v) {
    return __int_as_float(__builtin_amdgcn_mov_dpp(__float_as_int(v), 0x138, 0xf, 0xf, true));
}

// R12 structure (two neurons per block: wave 0 interleaves both serial step
// chains for in-wave ILP; wave 1 produces both far fields), with ONE change:
// __launch_bounds__(128, 1). R12's counters (VGPR_Count=128, FETCH 49MB vs
// 3.2MB inputs) proved the allocator's 128-VGPR occupancy heuristic spilled
// ~46MB/dispatch of scratch into the serial loop, destroying the experiment.
// min-waves/EU=1 raises the budget to 512 so the ~200 live registers stay in
// the file. Grid supplies only 2 waves/SIMD anyway (<=256 VGPR keeps that).
// Per-neuron FP op order untouched => bit-identical (absmax 0.5).
__global__ __launch_bounds__(128, 1)
void flif_kernel(const float* __restrict__ I_old, const float* __restrict__ W,
                 float* __restrict__ out, float cm1, float c2, float c3, int Stot)
{
    const int tid  = threadIdx.x;
    const int wid  = tid >> 6;
    const int lane = tid & 63;
    const int nA   = 2 * blockIdx.x;      // neuron A row
    const int nB   = nA + 1;              // neuron B row

    __shared__ __align__(16) float wtr[4 * WS];       // wtr[r][k] = wt[k+r], wt[i]=wr[i+1]=W[4998-i]
    __shared__ __align__(16) float dbuf[2][T_STEPS];  // delta history per neuron
    __shared__ float accs[2][2][CH];                  // [neuron][target parity][lane]

    for (int k = tid; k < 4 * WS; k += 128) {
        const int r = k / WS, kk = k - r * WS;
        const int i = kk + r;
        wtr[k] = (i <= 382) ? W[4998 - i] : 0.0f;
    }
    ((float*)accs)[tid] = 0.0f;                       // zero all 256 floats
    ((float*)accs)[tid + 128] = 0.0f;
    __syncthreads();

    // ascending per-lane weight base: wlp[m] = wt[lane + m], 16B-aligned for m%4==0
    const int rl = lane & 3;
    const float* wlp = wtr + rl * WS + (lane - rl);

    if (wid == 1) {
        // -------- far-field producer wave: g>=2, source-major, BOTH neurons --------
        float A2a = 0, A3a = 0, A4a = 0, A5a = 0;
        float A2b = 0, A3b = 0, A4b = 0, A5b = 0;
        #pragma unroll
        for (int c = 0; c < NCH; ++c) {
            if (c >= 1 && c <= 4) {
                const int src = c - 1;                // deltas published at end of chunk c-1
                #pragma unroll
                for (int X = 0; X < 2; ++X) {
                    const float* dp = dbuf[X] + src * CH;
                    #pragma unroll
                    for (int k = 0; k <= 60; k += 4) {
                        const float4 d4 = *reinterpret_cast<const float4*>(dp + k);   // broadcast
                        #pragma unroll
                        for (int t = c + 1; t <= 5; ++t) {
                            const int g = t - src;                                    // 2..5
                            const float4 w4 = *reinterpret_cast<const float4*>(wlp + (g * 64 - k - 4));
                            float& At = (X == 0)
                                ? ((t == 2) ? A2a : (t == 3) ? A3a : (t == 4) ? A4a : A5a)
                                : ((t == 2) ? A2b : (t == 3) ? A3b : (t == 4) ? A4b : A5b);
                            At = fmaf(d4.x, w4.w, At);   // j ascending within each target
                            At = fmaf(d4.y, w4.z, At);
                            At = fmaf(d4.z, w4.y, At);
                            At = fmaf(d4.w, w4.x, At);
                        }
                    }
                    const float hand = (X == 0)
                        ? ((c == 1) ? A2a : (c == 2) ? A3a : (c == 3) ? A4a : A5a)
                        : ((c == 1) ? A2b : (c == 2) ? A3b : (c == 3) ? A4b : A5b);
                    accs[X][(c + 1) & 1][lane] = hand;   // target c+1 complete
                }
            }
            __syncthreads();
        }
        return;
    }

    // -------- step-loop wave (wid == 0): two interleaved neurons --------
    const float* IrowA = I_old + (size_t)nA * T_STEPS;
    const float* IrowB = I_old + (size_t)nB * T_STEPS;
    float InextA = IrowA[lane];
    float InextB = IrowB[lane];
    const float w0   = (lane >= 1) ? W[4999 - lane] : 0.0f;  // wr[lane], wr[0]=0
    const float wr1n = -W[4998];                             // -wr[1]

    float VA = 0, dA = 0, bA = 0, PA = 0;
    float VB = 0, dB = 0, bB = 0, PB = 0;
    float tcsA[NCH], spksA[NCH], tcsB[NCH], spksB[NCH];

    for (int c = 0; c < NCH; ++c) {
        const int cb = c * CH;
        const float IcA = InextA, IcB = InextB;
        if (c + 1 < NCH) { InextA = IrowA[cb + CH + lane]; InextB = IrowB[cb + CH + lane]; }

        // ---- far field: g>=2 partial from producer, then append g=1 (j ascending) ----
        float accA = (c == 0) ? 0.0f : accs[0][c & 1][lane];
        float accB = (c == 0) ? 0.0f : accs[1][c & 1][lane];
        if (c >= 1) {
            const float* dpA = dbuf[0] + (c - 1) * CH;
            const float* dpB = dbuf[1] + (c - 1) * CH;
            #pragma unroll
            for (int m0 = 60; m0 >= 0; m0 -= 4) {
                const float4 w4 = *reinterpret_cast<const float4*>(wlp + m0);          // shared
                const float4 a4 = *reinterpret_cast<const float4*>(dpA + (60 - m0));   // broadcast
                const float4 b4 = *reinterpret_cast<const float4*>(dpB + (60 - m0));
                accA = fmaf(a4.x, w4.w, accA);  accB = fmaf(b4.x, w4.w, accB);
                accA = fmaf(a4.y, w4.z, accA);  accB = fmaf(b4.y, w4.z, accB);
                accA = fmaf(a4.z, w4.y, accA);  accB = fmaf(b4.z, w4.y, accB);
                accA = fmaf(a4.w, w4.x, accA);  accB = fmaf(b4.w, w4.x, accB);
            }
        }

        float uA = fmaf(c3, IcA, c2) - accA;
        float uB = fmaf(c3, IcB, c2) - accB;
        const float VsA = VA, VsB = VB;
        float tcA = 0.0f, tcB = 0.0f;
        float wA = w0, wB = w0;

        auto body = [&](int i) {
            // neuron A                                  // neuron B (independent -> ILP)
            const float tA = fmaf(wr1n, dA, PA);         const float tB = fmaf(wr1n, dB, PB);
            dA = tA + bA;                                dB = tB + bB;
            PA = readlane_f(uA, (i + 1) & 63);           PB = readlane_f(uB, (i + 1) & 63);
            VA = VA + dA;                                VB = VB + dB;
            const float rA = (VA > -50.0f) ? -20.0f : 0.0f;
            const float rB = (VB > -50.0f) ? -20.0f : 0.0f;
            bA = fmaf(cm1, VA, rA);                      bB = fmaf(cm1, VB, rB);
            uA = fmaf(-wA, dA, uA);                      uB = fmaf(-wB, dB, uB);
            wA = wave_shr1_f(wA);                        wB = wave_shr1_f(wB);
            tcA = (lane == i) ? VA : tcA;                tcB = (lane == i) ? VB : tcB;
        };

        if (c == 0) {
            // step 0: V_prev=0 -> spike, V_pre=-70, V_new=-90; delta masked out
            VA = -90.0f; VB = -90.0f;
            if (lane == 0) { tcA = VA; tcB = VB; }
            wA = wave_shr1_f(wA); wB = wave_shr1_f(wB);  // -> wr[lane-1]
            // step 1: V1 rule (no memory); V=-90 -> no reset
            const float I1A = readlane_f(IcA, 1);
            const float I1B = readlane_f(IcB, 1);
            const float V1A = fmaf(0.005f, (I1A / 0.025f) - VA, VA);
            const float V1B = fmaf(0.005f, (I1B / 0.025f) - VB, VB);
            const float d1A = V1A - VA, d1B = V1B - VB;
            PA = readlane_f(uA, 2); PB = readlane_f(uB, 2);
            uA = fmaf(-wA, d1A, uA); uB = fmaf(-wB, d1B, uB);
            wA = wave_shr1_f(wA); wB = wave_shr1_f(wB);  // -> wr[lane-2]
            if (lane == 1) { tcA = V1A; tcB = V1B; }
            VA = V1A; VB = V1B; dA = d1A; dB = d1B;
            bA = fmaf(cm1, VA, (VA > -50.0f) ? -20.0f : 0.0f);
            bB = fmaf(cm1, VB, (VB > -50.0f) ? -20.0f : 0.0f);
            #pragma unroll
            for (int i = 2; i < CH; ++i) body(i);
        } else {
            dA = 0.0f; dB = 0.0f;                        // wr[1]*d_{cb-1} already in far field
            PA = readlane_f(uA, 0); PB = readlane_f(uB, 0);
            #pragma unroll
            for (int i = 0; i < CH; ++i) body(i);
        }

        // ---- chunk epilogue: prev-V per lane -> spike, delta; publish dbuf ----
        float prevA = __shfl_up(tcA, 1);
        float prevB = __shfl_up(tcB, 1);
        if (lane == 0) { prevA = VsA; prevB = VsB; }
        spksA[c] = (prevA > -50.0f) ? 1.0f : 0.0f;
        spksB[c] = (prevB > -50.0f) ? 1.0f : 0.0f;
        float ddA = tcA - prevA, ddB = tcB - prevB;
        if (c == 0 && lane == 0) { ddA = 0.0f; ddB = 0.0f; }   // delta_0 excluded
        dbuf[0][cb + lane] = ddA;
        dbuf[1][cb + lane] = ddB;
        tcsA[c] = tcA; tcsB[c] = tcB;
        __syncthreads();                                 // publish dbuf / consume accs
    }

    // ---- deferred global stores (off the barrier path) ----
    float* spkA = out + (size_t)nA * T_STEPS;
    float* spkB = out + (size_t)nB * T_STEPS;
    float* trcA = out + (size_t)Stot * T_STEPS + (size_t)nA * T_STEPS;
    float* trcB = out + (size_t)Stot * T_STEPS + (size_t)nB * T_STEPS;
    #pragma unroll
    for (int c = 0; c < NCH; ++c) {
        spkA[c * CH + lane] = spksA[c];
        spkB[c * CH + lane] = spksB[c];
        trcA[c * CH + lane] = tcsA[c];
        trcB[c * CH + lane] = tcsB[c];
    }
}

extern "C" void kernel_launch(void* const* d_in, const int* in_sizes, int n_in,
                              void* d_out, int out_size, void* d_ws, size_t ws_size,
                              hipStream_t stream) {
    const float* I = (const float*)d_in[0];
    const float* W = (const float*)d_in[1];
    float* out = (float*)d_out;
    const int S = in_sizes[0] / T_STEPS;   // 2048

    const double COEF = std::pow(0.1, 0.15) * std::tgamma(1.85) / 0.5;
    const float c3  = (float)COEF;                     // COEF
    const float cm1 = (float)(-COEF * 0.025);          // c1 - 1 = -COEF*GL
    const float c2  = (float)(COEF * 0.025 * -70.0);   // COEF*GL*VL

    flif_kernel<<<S / 2, 128, 0, stream>>>(I, W, out, cm1, c2, c3, S);
}

// Round 14
// 76.225 us; speedup vs baseline: 1.8472x; 1.4702x over previous
//
#include <hip/hip_runtime.h>
#include <cmath>

#define T_STEPS 384
#define CH 64
#define NCH 6
#define WS 392

__device__ __forceinline__ float readlane_f(float v, int l) {
    return __int_as_float(__builtin_amdgcn_readlane(__float_as_int(v), l));
}
// DPP wave shift-right by 1: dst lane i = src lane i-1, lane 0 = 0 (bound_ctrl).
__device__ __forceinline__ float wave_shr1_f(float v) {
    return __int_as_float(__builtin_amdgcn_mov_dpp(__float_as_int(v), 0x138, 0xf, 0xf, true));
}

// R9 skeleton (2 waves/neuron: producer computes g>=2 far field) with the step
// wave's serial loop replaced by SPECULATIVE LINEARIZATION. R13's counters
// proved the ~150cyc/step floor is exposed latency of the 5-op serial cycle
// (d->V->cmp->sel->b->d, VCC in the loop). With no spike (5-sigma event), the
// recurrence is linear: d_n = P*_n + b2*d_{n-2} + b1*d_{n-1}, b_k = cm1-wr[k];
// cm1*V feedback folds into the scatter weight (cm1-wr[.]) (DPP-marched,
// zero-fill) + one cm1*V_cs constant in u. Serial cycle = ONE fma; readlane
// has 2-step slack; zero cmp/sel in the loop. Post-chunk margin check
// __any(V > -50.5): if any lane is near threshold, replay the chunk with the
// VERBATIM R9 exact body from the saved u0 (exact spike semantics). rv carry
// across chunks handled via rvprev folded into the first P.
__global__ __launch_bounds__(128, 4)
void flif_kernel(const float* __restrict__ I_old, const float* __restrict__ W,
                 float* __restrict__ out, float cm1, float c2, float c3, int Stot)
{
    const int tid  = threadIdx.x;
    const int wid  = tid >> 6;
    const int lane = tid & 63;
    const int s    = blockIdx.x;

    __shared__ __align__(16) float wtr[4 * WS];     // wtr[r][k] = wt[k+r], wt[i]=wr[i+1]=W[4998-i]
    __shared__ __align__(16) float dbuf[T_STEPS];   // delta history
    __shared__ float accs[2][CH];                   // g>=2 partial handoff

    for (int k = tid; k < 4 * WS; k += 128) {
        const int r = k / WS, kk = k - r * WS;
        const int i = kk + r;
        wtr[k] = (i <= 382) ? W[4998 - i] : 0.0f;
    }
    ((float*)accs)[tid] = 0.0f;
    __syncthreads();

    const int rl = lane & 3;
    const float* wlp = wtr + rl * WS + (lane - rl);

    if (wid == 1) {
        // -------- far-field producer wave (g>=2, source-major) — verbatim R9 --------
        float A2 = 0.0f, A3 = 0.0f, A4 = 0.0f, A5 = 0.0f;
        #pragma unroll
        for (int c = 0; c < NCH; ++c) {
            if (c >= 1 && c <= 4) {
                const int src = c - 1;
                const float* dp = dbuf + src * CH;
                #pragma unroll
                for (int k = 0; k <= 60; k += 4) {
                    const float4 d4 = *reinterpret_cast<const float4*>(dp + k);
                    #pragma unroll
                    for (int t = c + 1; t <= 5; ++t) {
                        const int g = t - src;
                        const float4 w4 = *reinterpret_cast<const float4*>(wlp + (g * 64 - k - 4));
                        float& At = (t == 2) ? A2 : (t == 3) ? A3 : (t == 4) ? A4 : A5;
                        At = fmaf(d4.x, w4.w, At);
                        At = fmaf(d4.y, w4.z, At);
                        At = fmaf(d4.z, w4.y, At);
                        At = fmaf(d4.w, w4.x, At);
                    }
                }
                const float hand = (c == 1) ? A2 : (c == 2) ? A3 : (c == 3) ? A4 : A5;
                accs[(c + 1) & 1][lane] = hand;
            }
            __syncthreads();
        }
        return;
    }

    // -------- step-loop wave (wid == 0) --------
    const float* Irow = I_old + (size_t)s * T_STEPS;
    float Inext = Irow[lane];
    const float w0seed = (lane >= 1) ? W[4999 - lane] : 0.0f;   // wr[lane] (exact-path march)
    const float wr1n = -W[4998];                                 // -wr[1]
    const float b1 = cm1 - W[4998];                              // cm1 - wr[1]
    const float b2 = cm1 - W[4997];                              // cm1 - wr[2]
    const float w2seed = (lane >= 1) ? (cm1 - W[4999 - lane]) : 0.0f;  // spec scatter weight

    float Vcs = 0.0f;       // uniform chunk-entry V
    float rvprev = 0.0f;    // uniform reset term from previous chunk end
    float tcs[NCH], spks[NCH];

    for (int c = 0; c < NCH; ++c) {
        const int cb = c * CH;
        const float Ic = Inext;
        if (c + 1 < NCH) Inext = Irow[cb + CH + lane];

        // ---- far field: g>=2 partial from producer + g=1 pass (verbatim R9) ----
        float acc = (c == 0) ? 0.0f : accs[c & 1][lane];
        if (c >= 1) {
            const float* dp = dbuf + (c - 1) * CH;
            #pragma unroll
            for (int m0 = 60; m0 >= 0; m0 -= 4) {
                const float4 d4 = *reinterpret_cast<const float4*>(dp + (60 - m0));
                const float4 w4 = *reinterpret_cast<const float4*>(wlp + m0);
                acc = fmaf(d4.x, w4.w, acc);
                acc = fmaf(d4.y, w4.z, acc);
                acc = fmaf(d4.z, w4.y, acc);
                acc = fmaf(d4.w, w4.x, acc);
            }
        }

        const float u0 = fmaf(c3, Ic, c2) - acc;    // exact-basis t0 (saved for fallback)
        const float Vs = Vcs;
        float tc = 0.0f;
        float Vend;

        // ---------- speculative no-spike pass: serial cycle = 1 fma ----------
        {
            float u, S, Pq0, Pq1, w2;
            float dm1 = 0.0f, dm2 = 0.0f;
            if (c == 0) {
                // exact steps 0,1 (spike at 0, V1-rule at 1); Vcs = 0 so S == V
                float V0 = -90.0f;
                if (lane == 0) tc = V0;
                const float wf = wave_shr1_f(w0seed);        // wr[lane-1]
                const float I1 = readlane_f(Ic, 1);
                const float V1 = fmaf(0.005f, (I1 / 0.025f) - V0, V0);
                const float d1 = V1 - V0;
                const float ue = fmaf(-wf, d1, u0);          // exact scatter of d_1
                if (lane == 1) tc = V1;
                u = fmaf(cm1, V1, ue);                       // + cm1*V_pre constant
                S = V1;
                Pq0 = readlane_f(u, 2);                      // complete: taps are 0
                Pq1 = readlane_f(u, 3);
                w2 = wave_shr1_f(wave_shr1_f(w2seed));       // aligned for scattering d_2
                #pragma unroll
                for (int i = 2; i < CH; ++i) {
                    const float x  = fmaf(b2, dm2, (i & 1) ? Pq1 : Pq0);
                    const float dn = fmaf(b1, dm1, x);       // [the only serial cycle]
                    const float nf = readlane_f(u, (i + 2) & 63);   // BEFORE scatter
                    if (i & 1) Pq1 = nf; else Pq0 = nf;
                    u = fmaf(w2, dn, u);                     // scatter (cm1 - wr[.])*d
                    w2 = wave_shr1_f(w2);
                    S += dn;
                    tc = (lane == i) ? S : tc;
                    dm2 = dm1; dm1 = dn;
                }
                Vend = S;
            } else {
                u = fmaf(cm1, Vcs, u0);                      // + cm1*V_cs constant
                S = 0.0f;
                Pq0 = readlane_f(u, 0) + rvprev;             // chunk-boundary reset carry
                Pq1 = readlane_f(u, 1);
                w2 = w2seed;
                #pragma unroll
                for (int i = 0; i < CH; ++i) {
                    const float x  = fmaf(b2, dm2, (i & 1) ? Pq1 : Pq0);
                    const float dn = fmaf(b1, dm1, x);
                    const float nf = readlane_f(u, (i + 2) & 63);
                    if (i & 1) Pq1 = nf; else Pq0 = nf;
                    u = fmaf(w2, dn, u);
                    w2 = wave_shr1_f(w2);
                    S += dn;
                    tc = (lane == i) ? S : tc;
                    dm2 = dm1; dm1 = dn;
                }
                tc = Vcs + tc;                               // absolutize per-lane V
                Vend = Vcs + S;
            }
        }

        // ---------- margin check: any V near threshold -> exact replay ----------
        if (__any(tc > -50.5f)) {
            float V, d, b, P, w;
            float tcf = 0.0f;
            float uf = u0;
            if (c == 0) {
                V = -90.0f;
                if (lane == 0) tcf = V;
                w = wave_shr1_f(w0seed);
                const float I1 = readlane_f(Ic, 1);
                const float V1 = fmaf(0.005f, (I1 / 0.025f) - V, V);
                const float d1 = V1 - V;
                P = readlane_f(uf, 2);
                uf = fmaf(-w, d1, uf);
                w = wave_shr1_f(w);
                if (lane == 1) tcf = V1;
                V = V1; d = d1;
                b = fmaf(cm1, V, (V > -50.0f) ? -20.0f : 0.0f);
                #pragma unroll
                for (int i = 2; i < CH; ++i) {
                    const float t = fmaf(wr1n, d, P);
                    d = t + b;
                    P = readlane_f(uf, (i + 1) & 63);
                    V = V + d;
                    const float rv = (V > -50.0f) ? -20.0f : 0.0f;
                    b = fmaf(cm1, V, rv);
                    uf = fmaf(-w, d, uf);
                    w = wave_shr1_f(w);
                    tcf = (lane == i) ? V : tcf;
                }
            } else {
                V = Vcs; d = 0.0f;
                b = fmaf(cm1, Vcs, rvprev);
                w = w0seed;
                P = readlane_f(uf, 0);
                #pragma unroll
                for (int i = 0; i < CH; ++i) {
                    const float t = fmaf(wr1n, d, P);
                    d = t + b;
                    P = readlane_f(uf, (i + 1) & 63);
                    V = V + d;
                    const float rv = (V > -50.0f) ? -20.0f : 0.0f;
                    b = fmaf(cm1, V, rv);
                    uf = fmaf(-w, d, uf);
                    w = wave_shr1_f(w);
                    tcf = (lane == i) ? V : tcf;
                }
            }
            tc = tcf; Vend = V;
        }
        rvprev = (Vend > -50.0f) ? -20.0f : 0.0f;

        // ---- chunk epilogue: prev-V per lane -> spike, delta; publish dbuf ----
        float prev = __shfl_up(tc, 1);
        if (lane == 0) prev = Vs;
        spks[c] = (prev > -50.0f) ? 1.0f : 0.0f;
        float dd = tc - prev;
        if (c == 0 && lane == 0) dd = 0.0f;              // delta_0 excluded by reference
        dbuf[cb + lane] = dd;
        tcs[c] = tc;
        Vcs = Vend;
        __syncthreads();                                 // publish dbuf / consume accs
    }

    // ---- deferred global stores ----
    float* out_spk = out + (size_t)s * T_STEPS;
    float* out_trc = out + (size_t)Stot * T_STEPS + (size_t)s * T_STEPS;
    #pragma unroll
    for (int c = 0; c < NCH; ++c) {
        out_spk[c * CH + lane] = spks[c];
        out_trc[c * CH + lane] = tcs[c];
    }
}

extern "C" void kernel_launch(void* const* d_in, const int* in_sizes, int n_in,
                              void* d_out, int out_size, void* d_ws, size_t ws_size,
                              hipStream_t stream) {
    const float* I = (const float*)d_in[0];
    const float* W = (const float*)d_in[1];
    float* out = (float*)d_out;
    const int S = in_sizes[0] / T_STEPS;   // 2048

    const double COEF = std::pow(0.1, 0.15) * std::tgamma(1.85) / 0.5;
    const float c3  = (float)COEF;                     // COEF
    const float cm1 = (float)(-COEF * 0.025);          // c1 - 1 = -COEF*GL
    const float c2  = (float)(COEF * 0.025 * -70.0);   // COEF*GL*VL

    flif_kernel<<<S, 128, 0, stream>>>(I, W, out, cm1, c2, c3, S);
}